// Round 1
// baseline (362.824 us; speedup 1.0000x reference)
//
#include <hip/hip_runtime.h>
#include <stdint.h>

// Problem constants (L=512, B=32, E=1024, H=16, hd=64)
#define LSEQ 512
#define BATCH 32
#define EMB 1024
#define NHEAD 16
#define HDIM 64
#define TOK (LSEQ*BATCH)       // 16384
#define BHTOT (BATCH*NHEAD)    // 512

typedef __attribute__((ext_vector_type(8))) short short8;   // 8 bf16 (4 VGPR)
typedef __attribute__((ext_vector_type(4))) short short4v;  // 4 bf16
typedef __attribute__((ext_vector_type(4))) float f32x4;

__device__ __forceinline__ short f2bf(float f) {
  union { float f; uint32_t u; } v; v.f = f;
  uint32_t r = (v.u + 0x7fffu + ((v.u >> 16) & 1u)) >> 16;  // RNE
  return (short)r;
}

#if defined(__has_builtin)
#if __has_builtin(__builtin_amdgcn_global_load_lds)
#define HAVE_GLL 1
#endif
#endif

__device__ __forceinline__ void gload_lds16(const void* g, void* l) {
#ifdef HAVE_GLL
  __builtin_amdgcn_global_load_lds((const __attribute__((address_space(1))) void*)g,
                                   (__attribute__((address_space(3))) void*)l, 16, 0, 0);
#else
  *(short8*)l = *(const short8*)g;
#endif
}

// ---------------- cast weights (fold 1/8 q-scale into Wq and bias) ----------------
__global__ void cast_weights(const float* __restrict__ W, const float* __restrict__ Wo,
                             const float* __restrict__ bias,
                             short* __restrict__ Wb, short* __restrict__ Wob,
                             float* __restrict__ biasp)
{
  int i = blockIdx.x * 256 + threadIdx.x;   // float4 index; 786432 (W) + 262144 (Wo)
  if (i < 786432) {
    f32x4 v = ((const f32x4*)W)[i];
    int row = i >> 8;                       // /256 float4 per row of 1024
    float s = (row < 1024) ? 0.125f : 1.0f; // 1/sqrt(64) folded into Wq
    short4v o;
    o[0] = f2bf(v[0]*s); o[1] = f2bf(v[1]*s); o[2] = f2bf(v[2]*s); o[3] = f2bf(v[3]*s);
    ((short4v*)Wb)[i] = o;
  } else {
    int j = i - 786432;
    f32x4 v = ((const f32x4*)Wo)[j];
    short4v o;
    o[0] = f2bf(v[0]); o[1] = f2bf(v[1]); o[2] = f2bf(v[2]); o[3] = f2bf(v[3]);
    ((short4v*)Wob)[j] = o;
  }
  if (i < 768) {                            // 3072 bias floats
    f32x4 v = ((const f32x4*)bias)[i];
    float s = (i < 256) ? 0.125f : 1.0f;
    f32x4 o = {v[0]*s, v[1]*s, v[2]*s, v[3]*s};
    ((f32x4*)biasp)[i] = o;
  }
}

// ---------------- mask (int32 0/1) -> bitmask, 1 bit/elem via ballot ----------------
__global__ void maskbits_kernel(const int* __restrict__ mask, uint32_t* __restrict__ mb)
{
  int w = (blockIdx.x * 256 + threadIdx.x) >> 6;   // row id 0..16383 (= b*512 + l)
  int lane = threadIdx.x & 63;
  const int* src = mask + ((size_t)w << 9);
  uint32_t* dst = mb + w * 16;
  #pragma unroll
  for (int c = 0; c < 8; ++c) {
    int v = src[c * 64 + lane];
    unsigned long long m = __ballot(v != 0);
    if (lane == 0) dst[c*2]     = (uint32_t)m;
    if (lane == 1) dst[c*2 + 1] = (uint32_t)(m >> 32);
  }
}

// ---------------- in-projection GEMM: C[t, headmajor] = bf16(x @ W^T + b) ----------------
// 128x128 tile, BK=32, 4 waves (2x2 of 64x64), 16x16x32 bf16 MFMA.
// A (f32) reg-staged with on-the-fly bf16 convert; B (bf16) via global_load_lds
// with pre-swizzled source. XOR chunk swizzle (c ^= row&3) caps frag-read conflicts.
__launch_bounds__(256, 2)
__global__ void proj_gemm(const float* __restrict__ Aq, const float* __restrict__ Ak,
                          const float* __restrict__ Av, const short* __restrict__ W,
                          const float* __restrict__ biasp,
                          short* __restrict__ qh, short* __restrict__ kh,
                          short* __restrict__ vh)
{
  int z = blockIdx.z;
  const float* A = (z == 0) ? Aq : (z == 1) ? Ak : Av;
  short* C       = (z == 0) ? qh : (z == 1) ? kh : vh;
  const short* B = W + (size_t)z * 1024 * 1024;
  const float* bp = biasp + z * 1024;

  // bijective XCD swizzle: the 8 bn-blocks sharing an A panel land on one XCD
  int flat = blockIdx.y * 8 + blockIdx.x;          // 0..1023
  int X = flat & 7, s = flat >> 3;
  int m0 = (X * 16 + (s >> 3)) * 128;
  int n0 = (s & 7) * 128;

  __shared__ alignas(16) short As[128 * 32];
  __shared__ alignas(16) short Bs[128 * 32];

  const int tid = threadIdx.x, lane = tid & 63;
  const int w = tid >> 6;
  const int wm = (w >> 1) * 64, wn = (w & 1) * 64;
  const int l15 = lane & 15, l4 = lane >> 4;

  f32x4 acc[4][4];
  #pragma unroll
  for (int mi = 0; mi < 4; ++mi)
    #pragma unroll
    for (int ni = 0; ni < 4; ++ni) acc[mi][ni] = f32x4{0.f, 0.f, 0.f, 0.f};

  for (int k0 = 0; k0 < 1024; k0 += 32) {
    __syncthreads();
    #pragma unroll
    for (int jj = 0; jj < 2; ++jj) {
      int ch = tid + jj * 256;          // chunk 0..511 (8 bf16 = 16B each)
      int row = ch >> 2, cl = ch & 3;
      int cs = cl ^ (row & 3);
      // A: f32 -> bf16 reg-staged, write at swizzled position
      const float* ga = A + (size_t)(m0 + row) * 1024 + k0 + cl * 8;
      f32x4 x0 = *(const f32x4*)ga;
      f32x4 x1 = *(const f32x4*)(ga + 4);
      short8 o;
      o[0] = f2bf(x0[0]); o[1] = f2bf(x0[1]); o[2] = f2bf(x0[2]); o[3] = f2bf(x0[3]);
      o[4] = f2bf(x1[0]); o[5] = f2bf(x1[1]); o[6] = f2bf(x1[2]); o[7] = f2bf(x1[3]);
      *(short8*)&As[row * 32 + cs * 8] = o;
      // B: linear LDS dest, pre-swizzled global source
      const short* gb = B + (size_t)(n0 + row) * 1024 + k0 + cs * 8;
      gload_lds16(gb, &Bs[ch * 8]);
    }
    __syncthreads();

    short8 af[4], bfr[4];
    #pragma unroll
    for (int mi = 0; mi < 4; ++mi) {
      int row = wm + mi * 16 + l15;
      int cs = l4 ^ (row & 3);
      af[mi] = *(const short8*)&As[row * 32 + cs * 8];
    }
    #pragma unroll
    for (int ni = 0; ni < 4; ++ni) {
      int row = wn + ni * 16 + l15;
      int cs = l4 ^ (row & 3);
      bfr[ni] = *(const short8*)&Bs[row * 32 + cs * 8];
    }
    #pragma unroll
    for (int mi = 0; mi < 4; ++mi)
      #pragma unroll
      for (int ni = 0; ni < 4; ++ni)
        acc[mi][ni] = __builtin_amdgcn_mfma_f32_16x16x32_bf16(af[mi], bfr[ni], acc[mi][ni], 0, 0, 0);
  }

  // epilogue: head-major bf16  dst[((b*H+h)*512 + lseq)*64 + d]
  #pragma unroll
  for (int ni = 0; ni < 4; ++ni) {
    int gcol = n0 + wn + ni * 16 + l15;
    float bv = bp[gcol];
    int h = gcol >> 6, d = gcol & 63;
    #pragma unroll
    for (int mi = 0; mi < 4; ++mi) {
      int growb = m0 + wm + mi * 16 + l4 * 4;
      #pragma unroll
      for (int r = 0; r < 4; ++r) {
        int grow = growb + r;                 // token index t = lseq*32 + b
        int lsq = grow >> 5, bb = grow & 31;
        C[((size_t)((bb * NHEAD + h) * LSEQ + lsq)) * HDIM + d] = f2bf(acc[mi][ni][r] + bv);
      }
    }
  }
}

// ---------------- flash attention: 1 WG = (b,h, 64 q rows); 4 waves x 16 rows ----------------
__launch_bounds__(256, 2)
__global__ void attn_kernel(const short* __restrict__ qh, const short* __restrict__ kh,
                            const short* __restrict__ vh, const uint32_t* __restrict__ mb,
                            short* __restrict__ ao)
{
  int flat = blockIdx.y * 8 + blockIdx.x;      // 0..4095
  int X = flat & 7, s = flat >> 3;
  int bh = X * 64 + (s >> 3);                  // 8 qblks of same bh share one XCD L2
  int qblk = s & 7;
  int b = bh >> 4, h = bh & 15;
  int q0 = qblk * 64;

  const int tid = threadIdx.x, lane = tid & 63, w = tid >> 6;
  const int l15 = lane & 15, l4 = lane >> 4;

  __shared__ alignas(16) short Ks[64 * 64];        // [kv][d], chunk-XOR swizzled
  __shared__ alignas(16) short Vt[64 * 72];        // [d][kv], pad 72 (2-way banks)
  __shared__ alignas(16) short Ps[4 * 16 * 72];    // per-wave P, pad 72
  __shared__ uint32_t Mw[64 * 2];

  const size_t bhoff = (size_t)bh * (LSEQ * HDIM);

  // Q fragments in registers (1/8 scale already folded into W/bias)
  short8 aq[2];
  {
    int qrow = q0 + w * 16 + l15;
    const short* qp = qh + bhoff + (size_t)qrow * HDIM + l4 * 8;
    aq[0] = *(const short8*)qp;
    aq[1] = *(const short8*)(qp + 32);
  }

  f32x4 oacc[4];
  #pragma unroll
  for (int n = 0; n < 4; ++n) oacc[n] = f32x4{0.f, 0.f, 0.f, 0.f};
  float m_i[4], l_i[4];
  #pragma unroll
  for (int r = 0; r < 4; ++r) { m_i[r] = -1e30f; l_i[r] = 0.f; }

  for (int kt = 0; kt < 8; ++kt) {
    __syncthreads();
    // stage K [64][64] with XOR-swizzled source (linear LDS dest for gload_lds)
    #pragma unroll
    for (int jj = 0; jj < 2; ++jj) {
      int ch = tid + jj * 256;               // 0..511, 16B chunks
      int row = ch >> 3, cl = ch & 7;
      int cg = cl ^ (row & 7);
      const short* g = kh + bhoff + (size_t)(kt * 64 + row) * HDIM + cg * 8;
      gload_lds16(g, &Ks[ch * 8]);
    }
    // stage V transposed: Vt[d][kv]
    #pragma unroll
    for (int jj = 0; jj < 2; ++jj) {
      int c = tid + jj * 256;
      int kv = c & 63, d0 = (c >> 6) * 8;
      const short* g = vh + bhoff + (size_t)(kt * 64 + kv) * HDIM + d0;
      short8 vv = *(const short8*)g;
      #pragma unroll
      for (int j = 0; j < 8; ++j) Vt[(d0 + j) * 72 + kv] = vv[j];
    }
    // stage mask words: 64 q-rows x 2 words (64 kv bits)
    if (tid < 128) {
      int qr = tid >> 1, wd = tid & 1;
      Mw[qr * 2 + wd] = mb[((size_t)b * LSEQ + q0 + qr) * 16 + kt * 2 + wd];
    }
    __syncthreads();

    // S = Q @ K^T   (16 q rows x 64 kv per wave)
    f32x4 sa[4];
    #pragma unroll
    for (int n = 0; n < 4; ++n) sa[n] = f32x4{0.f, 0.f, 0.f, 0.f};
    #pragma unroll
    for (int ss = 0; ss < 2; ++ss) {
      #pragma unroll
      for (int n = 0; n < 4; ++n) {
        int row = n * 16 + l15;
        int cs = (ss * 4 + l4) ^ (row & 7);
        short8 bk = *(const short8*)&Ks[row * 64 + cs * 8];
        sa[n] = __builtin_amdgcn_mfma_f32_16x16x32_bf16(aq[ss], bk, sa[n], 0, 0, 0);
      }
    }

    // mask + online softmax (rows r -> q row 4*l4+r), P -> LDS bf16
    #pragma unroll
    for (int r = 0; r < 4; ++r) {
      int qr = w * 16 + l4 * 4 + r;
      uint32_t mlo = Mw[qr * 2], mhi = Mw[qr * 2 + 1];
      float sv[4];
      #pragma unroll
      for (int n = 0; n < 4; ++n) {
        int cc = n * 16 + l15;
        uint32_t bit = ((cc < 32 ? (mlo >> cc) : (mhi >> (cc - 32))) & 1u);
        sv[n] = bit ? -1e9f : sa[n][r];
      }
      float rmax = fmaxf(fmaxf(sv[0], sv[1]), fmaxf(sv[2], sv[3]));
      #pragma unroll
      for (int off = 1; off < 16; off <<= 1) rmax = fmaxf(rmax, __shfl_xor(rmax, off, 64));
      float mn = fmaxf(m_i[r], rmax);
      float sc = __expf(m_i[r] - mn);
      float p0 = __expf(sv[0] - mn), p1 = __expf(sv[1] - mn);
      float p2 = __expf(sv[2] - mn), p3 = __expf(sv[3] - mn);
      float rs = p0 + p1 + p2 + p3;
      #pragma unroll
      for (int off = 1; off < 16; off <<= 1) rs += __shfl_xor(rs, off, 64);
      l_i[r] = l_i[r] * sc + rs;
      m_i[r] = mn;
      #pragma unroll
      for (int n = 0; n < 4; ++n) oacc[n][r] *= sc;
      short* pp = &Ps[w * 1152 + (l4 * 4 + r) * 72];
      pp[0 * 16 + l15] = f2bf(p0);
      pp[1 * 16 + l15] = f2bf(p1);
      pp[2 * 16 + l15] = f2bf(p2);
      pp[3 * 16 + l15] = f2bf(p3);
    }

    // O += P @ V
    #pragma unroll
    for (int ss = 0; ss < 2; ++ss) {
      short8 pa = *(const short8*)&Ps[w * 1152 + l15 * 72 + ss * 32 + l4 * 8];
      #pragma unroll
      for (int n = 0; n < 4; ++n) {
        short8 bv = *(const short8*)&Vt[(n * 16 + l15) * 72 + ss * 32 + l4 * 8];
        oacc[n] = __builtin_amdgcn_mfma_f32_16x16x32_bf16(pa, bv, oacc[n], 0, 0, 0);
      }
    }
  }

  // epilogue: ao[t][h*64+d], t = qrow*32 + b
  #pragma unroll
  for (int r = 0; r < 4; ++r) {
    float inv = 1.0f / l_i[r];
    int qrow = q0 + w * 16 + l4 * 4 + r;
    size_t tbase = ((size_t)qrow * BATCH + b) * EMB + h * HDIM;
    #pragma unroll
    for (int n = 0; n < 4; ++n)
      ao[tbase + n * 16 + l15] = f2bf(oacc[n][r] * inv);
  }
}

// ---------------- out-projection GEMM: f32 out = ao(bf16) @ Wo^T + bo ----------------
__launch_bounds__(256, 2)
__global__ void out_gemm(const short* __restrict__ Ab, const short* __restrict__ W,
                         const float* __restrict__ bo, float* __restrict__ out)
{
  int flat = blockIdx.y * 8 + blockIdx.x;
  int X = flat & 7, s = flat >> 3;
  int m0 = (X * 16 + (s >> 3)) * 128;
  int n0 = (s & 7) * 128;

  __shared__ alignas(16) short As[128 * 32];
  __shared__ alignas(16) short Bs[128 * 32];

  const int tid = threadIdx.x, lane = tid & 63;
  const int w = tid >> 6;
  const int wm = (w >> 1) * 64, wn = (w & 1) * 64;
  const int l15 = lane & 15, l4 = lane >> 4;

  f32x4 acc[4][4];
  #pragma unroll
  for (int mi = 0; mi < 4; ++mi)
    #pragma unroll
    for (int ni = 0; ni < 4; ++ni) acc[mi][ni] = f32x4{0.f, 0.f, 0.f, 0.f};

  for (int k0 = 0; k0 < 1024; k0 += 32) {
    __syncthreads();
    #pragma unroll
    for (int jj = 0; jj < 2; ++jj) {
      int ch = tid + jj * 256;
      int row = ch >> 2, cl = ch & 3;
      int cs = cl ^ (row & 3);
      const short* ga = Ab + (size_t)(m0 + row) * 1024 + k0 + cs * 8;
      gload_lds16(ga, &As[ch * 8]);
      const short* gb = W + (size_t)(n0 + row) * 1024 + k0 + cs * 8;
      gload_lds16(gb, &Bs[ch * 8]);
    }
    __syncthreads();

    short8 af[4], bfr[4];
    #pragma unroll
    for (int mi = 0; mi < 4; ++mi) {
      int row = wm + mi * 16 + l15;
      int cs = l4 ^ (row & 3);
      af[mi] = *(const short8*)&As[row * 32 + cs * 8];
    }
    #pragma unroll
    for (int ni = 0; ni < 4; ++ni) {
      int row = wn + ni * 16 + l15;
      int cs = l4 ^ (row & 3);
      bfr[ni] = *(const short8*)&Bs[row * 32 + cs * 8];
    }
    #pragma unroll
    for (int mi = 0; mi < 4; ++mi)
      #pragma unroll
      for (int ni = 0; ni < 4; ++ni)
        acc[mi][ni] = __builtin_amdgcn_mfma_f32_16x16x32_bf16(af[mi], bfr[ni], acc[mi][ni], 0, 0, 0);
  }

  #pragma unroll
  for (int ni = 0; ni < 4; ++ni) {
    int gcol = n0 + wn + ni * 16 + l15;
    float bv = bo[gcol];
    #pragma unroll
    for (int mi = 0; mi < 4; ++mi) {
      int growb = m0 + wm + mi * 16 + l4 * 4;
      #pragma unroll
      for (int r = 0; r < 4; ++r)
        out[(size_t)(growb + r) * 1024 + gcol] = acc[mi][ni][r] + bv;
    }
  }
}

extern "C" void kernel_launch(void* const* d_in, const int* in_sizes, int n_in,
                              void* d_out, int out_size, void* d_ws, size_t ws_size,
                              hipStream_t stream) {
  const float* q_in = (const float*)d_in[0];
  const float* k_in = (const float*)d_in[1];
  const float* v_in = (const float*)d_in[2];
  const int*   mask = (const int*)d_in[3];
  const float* Wp   = (const float*)d_in[4];
  const float* bp   = (const float*)d_in[5];
  const float* Wo   = (const float*)d_in[6];
  const float* bo   = (const float*)d_in[7];
  // d_in[8] = num_heads (==16, hardcoded)

  char* ws = (char*)d_ws;
  short* Wb    = (short*)ws;    ws += (size_t)3072 * 1024 * 2;
  short* Wob   = (short*)ws;    ws += (size_t)1024 * 1024 * 2;
  float* biasp = (float*)ws;    ws += (size_t)3072 * 4;
  short* qh    = (short*)ws;    ws += (size_t)TOK * EMB * 2;
  short* kh    = (short*)ws;    ws += (size_t)TOK * EMB * 2;
  short* vh    = (short*)ws;    ws += (size_t)TOK * EMB * 2;
  short* ao    = (short*)ws;    ws += (size_t)TOK * EMB * 2;
  uint32_t* mb = (uint32_t*)ws; ws += (size_t)BATCH * LSEQ * 16 * 4;

  cast_weights<<<4096, 256, 0, stream>>>(Wp, Wo, bp, Wb, Wob, biasp);
  maskbits_kernel<<<4096, 256, 0, stream>>>(mask, mb);
  proj_gemm<<<dim3(8, 128, 3), 256, 0, stream>>>(q_in, k_in, v_in, Wb, biasp, qh, kh, vh);
  attn_kernel<<<dim3(8, 512), 256, 0, stream>>>(qh, kh, vh, mb, ao);
  out_gemm<<<dim3(8, 128), 256, 0, stream>>>(ao, Wob, bo, (float*)d_out);
}

// Round 4
// 357.707 us; speedup vs baseline: 1.0143x; 1.0143x over previous
//
#include <hip/hip_runtime.h>
#include <hip/hip_bf16.h>
#include <stdint.h>

// Problem constants (L=512, B=32, E=1024, H=16, hd=64)
#define LSEQ 512
#define BATCH 32
#define EMB 1024
#define NHEAD 16
#define HDIM 64
#define TOK (LSEQ*BATCH)       // 16384
#define BHTOT (BATCH*NHEAD)    // 512

typedef __attribute__((ext_vector_type(8))) short short8;   // 8 bf16 (4 VGPR)
typedef __attribute__((ext_vector_type(4))) short short4v;  // 4 bf16
typedef __attribute__((ext_vector_type(4))) float f32x4;

// native RNE f32->bf16 (compiler emits packed v_cvt_pk_bf16_f32 — m240)
__device__ __forceinline__ short f2bf(float f) {
  __hip_bfloat16 h = __float2bfloat16(f);
  union { __hip_bfloat16 h; short s; } u; u.h = h;
  return u.s;
}

#if defined(__has_builtin)
#if __has_builtin(__builtin_amdgcn_global_load_lds)
#define HAVE_GLL 1
#endif
#endif

__device__ __forceinline__ void gload_lds16(const void* g, void* l) {
#ifdef HAVE_GLL
  __builtin_amdgcn_global_load_lds((const __attribute__((address_space(1))) void*)g,
                                   (__attribute__((address_space(3))) void*)l, 16, 0, 0);
#else
  *(short8*)l = *(const short8*)g;
#endif
}

// ---------------- cast weights (fold 1/8 q-scale into Wq and bias) ----------------
__global__ void cast_weights(const float* __restrict__ W, const float* __restrict__ Wo,
                             const float* __restrict__ bias,
                             short* __restrict__ Wb, short* __restrict__ Wob,
                             float* __restrict__ biasp)
{
  int i = blockIdx.x * 256 + threadIdx.x;   // float4 index; 786432 (W) + 262144 (Wo)
  if (i < 786432) {
    f32x4 v = ((const f32x4*)W)[i];
    int row = i >> 8;                       // /256 float4 per row of 1024
    float s = (row < 1024) ? 0.125f : 1.0f; // 1/sqrt(64) folded into Wq
    short4v o;
    o[0] = f2bf(v[0]*s); o[1] = f2bf(v[1]*s); o[2] = f2bf(v[2]*s); o[3] = f2bf(v[3]*s);
    ((short4v*)Wb)[i] = o;
  } else {
    int j = i - 786432;
    f32x4 v = ((const f32x4*)Wo)[j];
    short4v o;
    o[0] = f2bf(v[0]); o[1] = f2bf(v[1]); o[2] = f2bf(v[2]); o[3] = f2bf(v[3]);
    ((short4v*)Wob)[j] = o;
  }
  if (i < 768) {                            // 3072 bias floats
    f32x4 v = ((const f32x4*)bias)[i];
    float s = (i < 256) ? 0.125f : 1.0f;
    f32x4 o = {v[0]*s, v[1]*s, v[2]*s, v[3]*s};
    ((f32x4*)biasp)[i] = o;
  }
}

// ---------------- mask (int32 0/1) -> bitmask, 1 bit/elem via ballot ----------------
__global__ void maskbits_kernel(const int* __restrict__ mask, uint32_t* __restrict__ mb)
{
  int w = (blockIdx.x * 256 + threadIdx.x) >> 6;   // row id 0..16383 (= b*512 + l)
  int lane = threadIdx.x & 63;
  const int* src = mask + ((size_t)w << 9);
  uint32_t* dst = mb + w * 16;
  #pragma unroll
  for (int c = 0; c < 8; ++c) {
    int v = src[c * 64 + lane];
    unsigned long long m = __ballot(v != 0);
    if (lane == 0) dst[c*2]     = (uint32_t)m;
    if (lane == 1) dst[c*2 + 1] = (uint32_t)(m >> 32);
  }
}

// ---------------- in-projection GEMM: C[t, headmajor] = bf16(x @ W^T + b) ----------------
// 128x128 tile, BK=32, 4 waves (2x2 of 64x64), 16x16x32 bf16 MFMA.
// A (f32) reg-staged with native bf16 convert; B (bf16) via global_load_lds
// with pre-swizzled source. Swizzle s(row)=(row>>1)&3 -> 2-way banks (free, m136).
__launch_bounds__(256, 4)
__global__ void proj_gemm(const float* __restrict__ Aq, const float* __restrict__ Ak,
                          const float* __restrict__ Av, const short* __restrict__ W,
                          const float* __restrict__ biasp,
                          short* __restrict__ qh, short* __restrict__ kh,
                          short* __restrict__ vh)
{
  int z = blockIdx.z;
  const float* A = (z == 0) ? Aq : (z == 1) ? Ak : Av;
  short* C       = (z == 0) ? qh : (z == 1) ? kh : vh;
  const short* B = W + (size_t)z * 1024 * 1024;
  const float* bp = biasp + z * 1024;

  // bijective XCD swizzle: the 8 bn-blocks sharing an A panel land on one XCD
  int flat = blockIdx.y * 8 + blockIdx.x;          // 0..1023
  int X = flat & 7, s = flat >> 3;
  int m0 = (X * 16 + (s >> 3)) * 128;
  int n0 = (s & 7) * 128;

  __shared__ alignas(16) short As[128 * 32];
  __shared__ alignas(16) short Bs[128 * 32];

  const int tid = threadIdx.x, lane = tid & 63;
  const int w = tid >> 6;
  const int wm = (w >> 1) * 64, wn = (w & 1) * 64;
  const int l15 = lane & 15, l4 = lane >> 4;

  f32x4 acc[4][4];
  #pragma unroll
  for (int mi = 0; mi < 4; ++mi)
    #pragma unroll
    for (int ni = 0; ni < 4; ++ni) acc[mi][ni] = f32x4{0.f, 0.f, 0.f, 0.f};

  for (int k0 = 0; k0 < 1024; k0 += 32) {
    __syncthreads();
    #pragma unroll
    for (int jj = 0; jj < 2; ++jj) {
      int ch = tid + jj * 256;          // chunk 0..511 (8 bf16 = 16B each)
      int row = ch >> 2, cl = ch & 3;
      int sw = (row >> 1) & 3;
      int cs = cl ^ sw;
      // A: f32 -> bf16 reg-staged, write at swizzled position
      const float* ga = A + (size_t)(m0 + row) * 1024 + k0 + cl * 8;
      f32x4 x0 = *(const f32x4*)ga;
      f32x4 x1 = *(const f32x4*)(ga + 4);
      short8 o;
      o[0] = f2bf(x0[0]); o[1] = f2bf(x0[1]); o[2] = f2bf(x0[2]); o[3] = f2bf(x0[3]);
      o[4] = f2bf(x1[0]); o[5] = f2bf(x1[1]); o[6] = f2bf(x1[2]); o[7] = f2bf(x1[3]);
      *(short8*)&As[row * 32 + cs * 8] = o;
      // B: linear LDS dest, pre-swizzled global source
      const short* gb = B + (size_t)(n0 + row) * 1024 + k0 + cs * 8;
      gload_lds16(gb, &Bs[ch * 8]);
    }
    __syncthreads();

    short8 af[4], bfr[4];
    #pragma unroll
    for (int mi = 0; mi < 4; ++mi) {
      int row = wm + mi * 16 + l15;
      int cs = l4 ^ ((row >> 1) & 3);
      af[mi] = *(const short8*)&As[row * 32 + cs * 8];
    }
    #pragma unroll
    for (int ni = 0; ni < 4; ++ni) {
      int row = wn + ni * 16 + l15;
      int cs = l4 ^ ((row >> 1) & 3);
      bfr[ni] = *(const short8*)&Bs[row * 32 + cs * 8];
    }
    #pragma unroll
    for (int mi = 0; mi < 4; ++mi)
      #pragma unroll
      for (int ni = 0; ni < 4; ++ni)
        acc[mi][ni] = __builtin_amdgcn_mfma_f32_16x16x32_bf16(af[mi], bfr[ni], acc[mi][ni], 0, 0, 0);
  }

  // epilogue: head-major bf16  dst[((b*H+h)*512 + lseq)*64 + d]
  #pragma unroll
  for (int ni = 0; ni < 4; ++ni) {
    int gcol = n0 + wn + ni * 16 + l15;
    float bv = bp[gcol];
    int h = gcol >> 6, d = gcol & 63;
    #pragma unroll
    for (int mi = 0; mi < 4; ++mi) {
      int growb = m0 + wm + mi * 16 + l4 * 4;
      #pragma unroll
      for (int r = 0; r < 4; ++r) {
        int grow = growb + r;                 // token index t = lseq*32 + b
        int lsq = grow >> 5, bb = grow & 31;
        C[((size_t)((bb * NHEAD + h) * LSEQ + lsq)) * HDIM + d] = f2bf(acc[mi][ni][r] + bv);
      }
    }
  }
}

// ---------------- flash attention: 1 WG = (b,h, 64 q rows); 4 waves x 16 rows ----------------
__launch_bounds__(256, 2)
__global__ void attn_kernel(const short* __restrict__ qh, const short* __restrict__ kh,
                            const short* __restrict__ vh, const uint32_t* __restrict__ mb,
                            short* __restrict__ ao)
{
  int flat = blockIdx.y * 8 + blockIdx.x;      // 0..4095
  int X = flat & 7, s = flat >> 3;
  int bh = X * 64 + (s >> 3);                  // 8 qblks of same bh share one XCD L2
  int qblk = s & 7;
  int b = bh >> 4, h = bh & 15;
  int q0 = qblk * 64;

  const int tid = threadIdx.x, lane = tid & 63, w = tid >> 6;
  const int l15 = lane & 15, l4 = lane >> 4;

  __shared__ alignas(16) short Ks[64 * 64];        // [kv][d], chunk-XOR swizzled
  __shared__ alignas(16) short Vt[64 * 72];        // [d][kv], pad 72 (2-way banks)
  __shared__ alignas(16) short Ps[4 * 16 * 72];    // per-wave P, pad 72
  __shared__ uint32_t Mw[64 * 2];

  const size_t bhoff = (size_t)bh * (LSEQ * HDIM);

  // Q fragments in registers (1/8 scale already folded into W/bias)
  short8 aq[2];
  {
    int qrow = q0 + w * 16 + l15;
    const short* qp = qh + bhoff + (size_t)qrow * HDIM + l4 * 8;
    aq[0] = *(const short8*)qp;
    aq[1] = *(const short8*)(qp + 32);
  }

  f32x4 oacc[4];
  #pragma unroll
  for (int n = 0; n < 4; ++n) oacc[n] = f32x4{0.f, 0.f, 0.f, 0.f};
  float m_i[4], l_i[4];
  #pragma unroll
  for (int r = 0; r < 4; ++r) { m_i[r] = -1e30f; l_i[r] = 0.f; }

  for (int kt = 0; kt < 8; ++kt) {
    __syncthreads();
    // stage K [64][64] with XOR-swizzled source (linear LDS dest for gload_lds)
    #pragma unroll
    for (int jj = 0; jj < 2; ++jj) {
      int ch = tid + jj * 256;               // 0..511, 16B chunks
      int row = ch >> 3, cl = ch & 7;
      int cg = cl ^ (row & 7);
      const short* g = kh + bhoff + (size_t)(kt * 64 + row) * HDIM + cg * 8;
      gload_lds16(g, &Ks[ch * 8]);
    }
    // stage V transposed: Vt[d][kv]
    #pragma unroll
    for (int jj = 0; jj < 2; ++jj) {
      int c = tid + jj * 256;
      int kv = c & 63, d0 = (c >> 6) * 8;
      const short* g = vh + bhoff + (size_t)(kt * 64 + kv) * HDIM + d0;
      short8 vv = *(const short8*)g;
      #pragma unroll
      for (int j = 0; j < 8; ++j) Vt[(d0 + j) * 72 + kv] = vv[j];
    }
    // stage mask words: 64 q-rows x 2 words (64 kv bits)
    if (tid < 128) {
      int qr = tid >> 1, wd = tid & 1;
      Mw[qr * 2 + wd] = mb[((size_t)b * LSEQ + q0 + qr) * 16 + kt * 2 + wd];
    }
    __syncthreads();

    // S = Q @ K^T   (16 q rows x 64 kv per wave)
    f32x4 sa[4];
    #pragma unroll
    for (int n = 0; n < 4; ++n) sa[n] = f32x4{0.f, 0.f, 0.f, 0.f};
    #pragma unroll
    for (int ss = 0; ss < 2; ++ss) {
      #pragma unroll
      for (int n = 0; n < 4; ++n) {
        int row = n * 16 + l15;
        int cs = (ss * 4 + l4) ^ (row & 7);
        short8 bk = *(const short8*)&Ks[row * 64 + cs * 8];
        sa[n] = __builtin_amdgcn_mfma_f32_16x16x32_bf16(aq[ss], bk, sa[n], 0, 0, 0);
      }
    }

    // mask + online softmax (rows r -> q row 4*l4+r), P -> LDS bf16
    #pragma unroll
    for (int r = 0; r < 4; ++r) {
      int qr = w * 16 + l4 * 4 + r;
      uint32_t mlo = Mw[qr * 2], mhi = Mw[qr * 2 + 1];
      float sv[4];
      #pragma unroll
      for (int n = 0; n < 4; ++n) {
        int cc = n * 16 + l15;
        uint32_t bit = ((cc < 32 ? (mlo >> cc) : (mhi >> (cc - 32))) & 1u);
        sv[n] = bit ? -1e9f : sa[n][r];
      }
      float rmax = fmaxf(fmaxf(sv[0], sv[1]), fmaxf(sv[2], sv[3]));
      #pragma unroll
      for (int off = 1; off < 16; off <<= 1) rmax = fmaxf(rmax, __shfl_xor(rmax, off, 64));
      float mn = fmaxf(m_i[r], rmax);
      float sc = __expf(m_i[r] - mn);
      float p0 = __expf(sv[0] - mn), p1 = __expf(sv[1] - mn);
      float p2 = __expf(sv[2] - mn), p3 = __expf(sv[3] - mn);
      float rs = p0 + p1 + p2 + p3;
      #pragma unroll
      for (int off = 1; off < 16; off <<= 1) rs += __shfl_xor(rs, off, 64);
      l_i[r] = l_i[r] * sc + rs;
      m_i[r] = mn;
      #pragma unroll
      for (int n = 0; n < 4; ++n) oacc[n][r] *= sc;
      short* pp = &Ps[w * 1152 + (l4 * 4 + r) * 72];
      pp[0 * 16 + l15] = f2bf(p0);
      pp[1 * 16 + l15] = f2bf(p1);
      pp[2 * 16 + l15] = f2bf(p2);
      pp[3 * 16 + l15] = f2bf(p3);
    }

    // O += P @ V
    #pragma unroll
    for (int ss = 0; ss < 2; ++ss) {
      short8 pa = *(const short8*)&Ps[w * 1152 + l15 * 72 + ss * 32 + l4 * 8];
      #pragma unroll
      for (int n = 0; n < 4; ++n) {
        short8 bv = *(const short8*)&Vt[(n * 16 + l15) * 72 + ss * 32 + l4 * 8];
        oacc[n] = __builtin_amdgcn_mfma_f32_16x16x32_bf16(pa, bv, oacc[n], 0, 0, 0);
      }
    }
  }

  // epilogue: ao[t][h*64+d], t = qrow*32 + b
  #pragma unroll
  for (int r = 0; r < 4; ++r) {
    float inv = 1.0f / l_i[r];
    int qrow = q0 + w * 16 + l4 * 4 + r;
    size_t tbase = ((size_t)qrow * BATCH + b) * EMB + h * HDIM;
    #pragma unroll
    for (int n = 0; n < 4; ++n)
      ao[tbase + n * 16 + l15] = f2bf(oacc[n][r] * inv);
  }
}

// ---------------- out-projection GEMM: f32 out = ao(bf16) @ Wo^T + bo ----------------
__launch_bounds__(256, 4)
__global__ void out_gemm(const short* __restrict__ Ab, const short* __restrict__ W,
                         const float* __restrict__ bo, float* __restrict__ out)
{
  int flat = blockIdx.y * 8 + blockIdx.x;
  int X = flat & 7, s = flat >> 3;
  int m0 = (X * 16 + (s >> 3)) * 128;
  int n0 = (s & 7) * 128;

  __shared__ alignas(16) short As[128 * 32];
  __shared__ alignas(16) short Bs[128 * 32];

  const int tid = threadIdx.x, lane = tid & 63;
  const int w = tid >> 6;
  const int wm = (w >> 1) * 64, wn = (w & 1) * 64;
  const int l15 = lane & 15, l4 = lane >> 4;

  f32x4 acc[4][4];
  #pragma unroll
  for (int mi = 0; mi < 4; ++mi)
    #pragma unroll
    for (int ni = 0; ni < 4; ++ni) acc[mi][ni] = f32x4{0.f, 0.f, 0.f, 0.f};

  for (int k0 = 0; k0 < 1024; k0 += 32) {
    __syncthreads();
    #pragma unroll
    for (int jj = 0; jj < 2; ++jj) {
      int ch = tid + jj * 256;
      int row = ch >> 2, cl = ch & 3;
      int cs = cl ^ ((row >> 1) & 3);
      const short* ga = Ab + (size_t)(m0 + row) * 1024 + k0 + cs * 8;
      gload_lds16(ga, &As[ch * 8]);
      const short* gb = W + (size_t)(n0 + row) * 1024 + k0 + cs * 8;
      gload_lds16(gb, &Bs[ch * 8]);
    }
    __syncthreads();

    short8 af[4], bfr[4];
    #pragma unroll
    for (int mi = 0; mi < 4; ++mi) {
      int row = wm + mi * 16 + l15;
      int cs = l4 ^ ((row >> 1) & 3);
      af[mi] = *(const short8*)&As[row * 32 + cs * 8];
    }
    #pragma unroll
    for (int ni = 0; ni < 4; ++ni) {
      int row = wn + ni * 16 + l15;
      int cs = l4 ^ ((row >> 1) & 3);
      bfr[ni] = *(const short8*)&Bs[row * 32 + cs * 8];
    }
    #pragma unroll
    for (int mi = 0; mi < 4; ++mi)
      #pragma unroll
      for (int ni = 0; ni < 4; ++ni)
        acc[mi][ni] = __builtin_amdgcn_mfma_f32_16x16x32_bf16(af[mi], bfr[ni], acc[mi][ni], 0, 0, 0);
  }

  #pragma unroll
  for (int ni = 0; ni < 4; ++ni) {
    int gcol = n0 + wn + ni * 16 + l15;
    float bv = bo[gcol];
    #pragma unroll
    for (int mi = 0; mi < 4; ++mi) {
      int growb = m0 + wm + mi * 16 + l4 * 4;
      #pragma unroll
      for (int r = 0; r < 4; ++r)
        out[(size_t)(growb + r) * 1024 + gcol] = acc[mi][ni][r] + bv;
    }
  }
}

extern "C" void kernel_launch(void* const* d_in, const int* in_sizes, int n_in,
                              void* d_out, int out_size, void* d_ws, size_t ws_size,
                              hipStream_t stream) {
  const float* q_in = (const float*)d_in[0];
  const float* k_in = (const float*)d_in[1];
  const float* v_in = (const float*)d_in[2];
  const int*   mask = (const int*)d_in[3];
  const float* Wp   = (const float*)d_in[4];
  const float* bp   = (const float*)d_in[5];
  const float* Wo   = (const float*)d_in[6];
  const float* bo   = (const float*)d_in[7];
  // d_in[8] = num_heads (==16, hardcoded)

  char* ws = (char*)d_ws;
  short* Wb    = (short*)ws;    ws += (size_t)3072 * 1024 * 2;
  short* Wob   = (short*)ws;    ws += (size_t)1024 * 1024 * 2;
  float* biasp = (float*)ws;    ws += (size_t)3072 * 4;
  short* qh    = (short*)ws;    ws += (size_t)TOK * EMB * 2;
  short* kh    = (short*)ws;    ws += (size_t)TOK * EMB * 2;
  short* vh    = (short*)ws;    ws += (size_t)TOK * EMB * 2;
  short* ao    = (short*)ws;    ws += (size_t)TOK * EMB * 2;
  uint32_t* mb = (uint32_t*)ws; ws += (size_t)BATCH * LSEQ * 16 * 4;

  cast_weights<<<4096, 256, 0, stream>>>(Wp, Wo, bp, Wb, Wob, biasp);
  maskbits_kernel<<<4096, 256, 0, stream>>>(mask, mb);
  proj_gemm<<<dim3(8, 128, 3), 256, 0, stream>>>(q_in, k_in, v_in, Wb, biasp, qh, kh, vh);
  attn_kernel<<<dim3(8, 512), 256, 0, stream>>>(qh, kh, vh, mb, ao);
  out_gemm<<<dim3(8, 128), 256, 0, stream>>>(ao, Wob, bo, (float*)d_out);
}